// Round 1
// baseline (2613.066 us; speedup 1.0000x reference)
//
#include <hip/hip_runtime.h>

// Problem constants (B,S,D,H fixed by the reference)
#define B_  4
#define S_  2048
#define D_  1024
#define H_  16
#define DK_ 64

// ---------------------------------------------------------------------------
// GEMM: out = x @ W^T + bias.   x:[M=8192,K=1024] row-major, W:[N=1024,K=1024]
// row-major (torch Linear convention) -> both operands are K-contiguous (NT).
// OUT_LAYOUT 0: scatter to [B,H,S,DK] (for Q/K/V projections)
// OUT_LAYOUT 1: flat [M,N] (final output projection)
// Tile 64x64, BK=16, 256 threads, 4x4 accum/thread.
// ---------------------------------------------------------------------------
template <int OUT_LAYOUT>
__global__ __launch_bounds__(256) void gemm_xwT(const float* __restrict__ x,
                                                const float* __restrict__ W,
                                                const float* __restrict__ bias,
                                                float* __restrict__ out) {
    __shared__ float As[16][65];  // As[k][m], +1 pad breaks stride-64 conflicts
    __shared__ float Ws[16][65];  // Ws[k][n]
    const int n0 = blockIdx.x * 64;
    const int m0 = blockIdx.y * 64;
    const int t  = threadIdx.x;
    const int tx = t & 15, ty = t >> 4;
    // loader: thread t fetches one float4 of A and of W per K-step
    const int lr = t >> 2;        // row within 64-tile
    const int lc = (t & 3) << 2;  // k-offset 0,4,8,12

    float acc[4][4] = {};
    for (int k0 = 0; k0 < D_; k0 += 16) {
        float4 av = *(const float4*)(x + (size_t)(m0 + lr) * D_ + k0 + lc);
        float4 wv = *(const float4*)(W + (size_t)(n0 + lr) * D_ + k0 + lc);
        As[lc + 0][lr] = av.x; As[lc + 1][lr] = av.y;
        As[lc + 2][lr] = av.z; As[lc + 3][lr] = av.w;
        Ws[lc + 0][lr] = wv.x; Ws[lc + 1][lr] = wv.y;
        Ws[lc + 2][lr] = wv.z; Ws[lc + 3][lr] = wv.w;
        __syncthreads();
#pragma unroll
        for (int kk = 0; kk < 16; ++kk) {
            float a[4], w[4];
#pragma unroll
            for (int i = 0; i < 4; ++i) a[i] = As[kk][ty * 4 + i];  // broadcast
#pragma unroll
            for (int j = 0; j < 4; ++j) w[j] = Ws[kk][tx * 4 + j];  // 2-way (free)
#pragma unroll
            for (int i = 0; i < 4; ++i)
#pragma unroll
                for (int j = 0; j < 4; ++j) acc[i][j] = fmaf(a[i], w[j], acc[i][j]);
        }
        __syncthreads();
    }
#pragma unroll
    for (int i = 0; i < 4; ++i) {
        const int m = m0 + ty * 4 + i;
#pragma unroll
        for (int j = 0; j < 4; ++j) {
            const int e = n0 + tx * 4 + j;
            const float v = acc[i][j] + bias[e];
            if (OUT_LAYOUT == 0) {
                const int b = m >> 11, s = m & (S_ - 1);
                const int h = e >> 6, dk = e & 63;
                out[((((size_t)b * H_ + h) * S_ + s) << 6) + dk] = v;
            } else {
                out[(size_t)m * D_ + e] = v;
            }
        }
    }
}

// ---------------------------------------------------------------------------
// Flash-style attention over [B,H,S,DK] Q/K/V. One block = one (b,h) x 64 Q
// rows; loops over K/V in 64-row tiles. Online softmax state (m,l) lives in
// registers; row reductions via 16-lane shuffle groups (rows are 16-aligned
// lane groups within a wave64). K-tile LDS is reused to hold P (keeps LDS at
// 49.4 KB -> 3 blocks/CU).
// ---------------------------------------------------------------------------
__global__ __launch_bounds__(256) void attn_kernel(const float* __restrict__ Qd,
                                                   const float* __restrict__ Kd,
                                                   const float* __restrict__ Vd,
                                                   const int* __restrict__ mask,
                                                   float* __restrict__ ctx) {
    __shared__ float KP[64][65];  // K tile (rows=k, cols=dk), later P tile (rows=q, cols=k)
    __shared__ float Vs[64][64];  // V tile (rows=k, cols=dk); unpadded reads are 2-way (free)
    __shared__ float Qt[64][64];  // Q transposed: Qt[dk][q-row] -> conflict-free broadcast reads

    const int bh = blockIdx.y;
    const int b = bh >> 4, h = bh & 15;
    const int q0 = blockIdx.x * 64;
    const int t  = threadIdx.x;
    const int tx = t & 15, ty = t >> 4;

    const float* Qb = Qd + (size_t)bh * S_ * DK_;
    const float* Kb = Kd + (size_t)bh * S_ * DK_;
    const float* Vb = Vd + (size_t)bh * S_ * DK_;
    const int*   mb = mask + (size_t)b * S_ * S_;

    // Load Q tile transposed (one-time; write conflicts here are amortized away)
#pragma unroll
    for (int p = 0; p < 4; ++p) {
        const int v = t + (p << 8);          // 0..1023 float4 index
        const int r = v >> 4, c = (v & 15) << 2;
        float4 qv = *(const float4*)(Qb + (size_t)(q0 + r) * DK_ + c);
        Qt[c + 0][r] = qv.x; Qt[c + 1][r] = qv.y;
        Qt[c + 2][r] = qv.z; Qt[c + 3][r] = qv.w;
    }

    float m_i[4], l_i[4], O[4][4] = {};
#pragma unroll
    for (int i = 0; i < 4; ++i) { m_i[i] = -3.0e38f; l_i[i] = 0.0f; }

    for (int k0 = 0; k0 < S_; k0 += 64) {
        __syncthreads();  // prior PV reads of KP/Vs done before overwrite
#pragma unroll
        for (int p = 0; p < 4; ++p) {
            const int v = t + (p << 8);
            const int r = v >> 4, c = (v & 15) << 2;
            float4 kv = *(const float4*)(Kb + (size_t)(k0 + r) * DK_ + c);
            KP[r][c + 0] = kv.x; KP[r][c + 1] = kv.y;
            KP[r][c + 2] = kv.z; KP[r][c + 3] = kv.w;
            float4 vv = *(const float4*)(Vb + (size_t)(k0 + r) * DK_ + c);
            *(float4*)(&Vs[r][c]) = vv;
        }
        __syncthreads();

        // scores: sc[i][j] = Q[q0+4ty+i] . K[k0+4tx+j]
        float sc[4][4] = {};
#pragma unroll 16
        for (int kk = 0; kk < 64; ++kk) {
            float q[4], k[4];
#pragma unroll
            for (int i = 0; i < 4; ++i) q[i] = Qt[kk][ty * 4 + i];
#pragma unroll
            for (int j = 0; j < 4; ++j) k[j] = KP[tx * 4 + j][kk];
#pragma unroll
            for (int i = 0; i < 4; ++i)
#pragma unroll
                for (int j = 0; j < 4; ++j) sc[i][j] = fmaf(q[i], k[j], sc[i][j]);
        }

        // scale + mask (mask==0 -> -1e9, exactly like reference)
#pragma unroll
        for (int i = 0; i < 4; ++i) {
            const int qg = q0 + ty * 4 + i;
            const int4 mv = *(const int4*)(mb + (size_t)qg * S_ + k0 + tx * 4);
            sc[i][0] = mv.x ? sc[i][0] * 0.125f : -1.0e9f;
            sc[i][1] = mv.y ? sc[i][1] * 0.125f : -1.0e9f;
            sc[i][2] = mv.z ? sc[i][2] * 0.125f : -1.0e9f;
            sc[i][3] = mv.w ? sc[i][3] * 0.125f : -1.0e9f;
        }

        // online softmax, all in registers; row = 16-lane shuffle group
        float alpha[4];
#pragma unroll
        for (int i = 0; i < 4; ++i) {
            float mx = fmaxf(fmaxf(sc[i][0], sc[i][1]), fmaxf(sc[i][2], sc[i][3]));
#pragma unroll
            for (int s = 8; s >= 1; s >>= 1) mx = fmaxf(mx, __shfl_xor(mx, s, 64));
            const float mnew = fmaxf(m_i[i], mx);
            alpha[i] = __expf(m_i[i] - mnew);
            float rs = 0.0f;
#pragma unroll
            for (int j = 0; j < 4; ++j) {
                sc[i][j] = __expf(sc[i][j] - mnew);
                rs += sc[i][j];
            }
#pragma unroll
            for (int s = 8; s >= 1; s >>= 1) rs += __shfl_xor(rs, s, 64);
            l_i[i] = l_i[i] * alpha[i] + rs;
            m_i[i] = mnew;
        }

        __syncthreads();  // all K reads done; reuse KP for P
#pragma unroll
        for (int i = 0; i < 4; ++i)
#pragma unroll
            for (int j = 0; j < 4; ++j) KP[ty * 4 + i][tx * 4 + j] = sc[i][j];
        __syncthreads();

        // O = alpha*O + P @ V
#pragma unroll
        for (int i = 0; i < 4; ++i)
#pragma unroll
            for (int j = 0; j < 4; ++j) O[i][j] *= alpha[i];
#pragma unroll 16
        for (int kk = 0; kk < 64; ++kk) {
            float p[4], v[4];
#pragma unroll
            for (int i = 0; i < 4; ++i) p[i] = KP[ty * 4 + i][kk];
#pragma unroll
            for (int j = 0; j < 4; ++j) v[j] = Vs[kk][tx * 4 + j];
#pragma unroll
            for (int i = 0; i < 4; ++i)
#pragma unroll
                for (int j = 0; j < 4; ++j) O[i][j] = fmaf(p[i], v[j], O[i][j]);
        }
    }

    // finalize: ctx[b][q][h*64+dk] = O / l   (ctx in [B,S,D] for the out-proj)
    float* cb = ctx + ((size_t)b * S_ + q0) * D_ + h * DK_;
#pragma unroll
    for (int i = 0; i < 4; ++i) {
        const float inv = 1.0f / l_i[i];
        float4 ov;
        ov.x = O[i][0] * inv; ov.y = O[i][1] * inv;
        ov.z = O[i][2] * inv; ov.w = O[i][3] * inv;
        *(float4*)(cb + (size_t)(ty * 4 + i) * D_ + tx * 4) = ov;
    }
}

// ---------------------------------------------------------------------------
extern "C" void kernel_launch(void* const* d_in, const int* in_sizes, int n_in,
                              void* d_out, int out_size, void* d_ws, size_t ws_size,
                              hipStream_t stream) {
    (void)in_sizes; (void)n_in; (void)out_size; (void)ws_size;
    const float* query = (const float*)d_in[0];
    const float* key_  = (const float*)d_in[1];
    const float* value = (const float*)d_in[2];
    const int*   mask  = (const int*)d_in[3];
    const float* Wq = (const float*)d_in[4];
    const float* bq = (const float*)d_in[5];
    const float* Wk = (const float*)d_in[6];
    const float* bk = (const float*)d_in[7];
    const float* Wv = (const float*)d_in[8];
    const float* bv = (const float*)d_in[9];
    const float* Wo = (const float*)d_in[10];
    const float* bo = (const float*)d_in[11];
    float* out = (float*)d_out;

    const size_t nQ = (size_t)B_ * H_ * S_ * DK_;  // 8,388,608 floats
    float* Qd  = (float*)d_ws;
    float* Kd  = Qd + nQ;
    float* Vd  = Kd + nQ;
    float* ctx = Vd + nQ;  // [B,S,D] layout; total ws use = 128 MiB

    dim3 gp(D_ / 64, (B_ * S_) / 64);  // (16,128)
    gemm_xwT<0><<<gp, 256, 0, stream>>>(query, Wq, bq, Qd);
    gemm_xwT<0><<<gp, 256, 0, stream>>>(key_,  Wk, bk, Kd);
    gemm_xwT<0><<<gp, 256, 0, stream>>>(value, Wv, bv, Vd);

    dim3 ga(S_ / 64, B_ * H_);  // (32,64)
    attn_kernel<<<ga, 256, 0, stream>>>(Qd, Kd, Vd, mask, ctx);

    gemm_xwT<1><<<gp, 256, 0, stream>>>(ctx, Wo, bo, out);
}

// Round 2
// 726.261 us; speedup vs baseline: 3.5980x; 3.5980x over previous
//
#include <hip/hip_runtime.h>

// Problem constants
#define B_  4
#define S_  2048
#define D_  1024
#define H_  16
#define DK_ 64

typedef unsigned short ushort;
typedef __attribute__((ext_vector_type(8))) short short8;
typedef __attribute__((ext_vector_type(8))) unsigned short ushort8;
typedef __attribute__((ext_vector_type(4))) float f32x4;

// fp32 -> bf16 round-to-nearest-even (bit manipulation; avoids hip_bf16 API)
__device__ __forceinline__ ushort f2bf(float f) {
    unsigned int u = __float_as_uint(f);
    u += 0x7fffu + ((u >> 16) & 1u);
    return (ushort)(u >> 16);
}

// async global->LDS, 16 bytes per lane. ldsbase must be wave-uniform; HW
// writes ldsbase + lane*16 (guide §5: m97/m104-verified semantics).
__device__ __forceinline__ void gl_lds16(const ushort* g, ushort* ldsbase) {
    __builtin_amdgcn_global_load_lds(
        (const __attribute__((address_space(1))) void*)g,
        (__attribute__((address_space(3))) void*)ldsbase, 16, 0, 0);
}

// ---------------------------------------------------------------------------
// Elementwise fp32 -> bf16 cast, 8 elems/thread
// ---------------------------------------------------------------------------
__global__ __launch_bounds__(256) void cast_bf16_x8(const float* __restrict__ x,
                                                    ushort* __restrict__ o, int n) {
    const int i = (blockIdx.x * 256 + threadIdx.x) * 8;
    if (i >= n) return;
    const float4 a = *(const float4*)(x + i);
    const float4 b = *(const float4*)(x + i + 4);
    ushort8 r;
    r[0] = f2bf(a.x); r[1] = f2bf(a.y); r[2] = f2bf(a.z); r[3] = f2bf(a.w);
    r[4] = f2bf(b.x); r[5] = f2bf(b.y); r[6] = f2bf(b.z); r[7] = f2bf(b.w);
    *(ushort8*)(o + i) = r;
}

// int32 mask -> u8 (0/1), 4 elems/thread packed into one u32 store
__global__ __launch_bounds__(256) void mask_to_u8(const int* __restrict__ m,
                                                  unsigned int* __restrict__ o, int n4) {
    const int i = blockIdx.x * 256 + threadIdx.x;
    if (i >= n4) return;
    const int4 v = ((const int4*)m)[i];
    o[i] = (v.x ? 1u : 0u) | (v.y ? 0x100u : 0u) | (v.z ? 0x10000u : 0u) |
           (v.w ? 0x1000000u : 0u);
}

// ---------------------------------------------------------------------------
// bf16 MFMA GEMM: out = A @ W^T + bias  (A:[8192,1024], W:[1024,1024], both
// K-contiguous row-major bf16). m97 structure: 128x128 tile, BK=32, async
// global->LDS staging, 16x16x32 MFMA, 4 waves in 2x2, 4x4 frags each.
// OUT_LAYOUT 0: bf16 scatter to [B,H,S,DK];  1: fp32 flat [M,N].
// ---------------------------------------------------------------------------
template <int OUT_LAYOUT>
__global__ __launch_bounds__(256) void gemm_bt_mfma(const ushort* __restrict__ A,
                                                    const ushort* __restrict__ Wm,
                                                    const float* __restrict__ bias,
                                                    void* __restrict__ outv) {
    __shared__ ushort As[128 * 32];  // [m][k] row-major, 8 KB (async layout: no pad)
    __shared__ ushort Bs[128 * 32];  // [n][k]
    const int t = threadIdx.x, w = t >> 6, lane = t & 63;
    const int ln15 = lane & 15, quad = lane >> 4;
    const int wr = w >> 1, wc = w & 1;
    const int n0 = blockIdx.x * 128, m0 = blockIdx.y * 128;
    const int srow = lane >> 2;      // staging: row within 16-row chunk
    const int sg = (lane & 3) * 8;   // staging: k-offset (elems)

    f32x4 acc[4][4] = {};
    for (int k0 = 0; k0 < D_; k0 += 32) {
#pragma unroll
        for (int c = 0; c < 2; ++c) {
            const int cc = w * 2 + c;
            const int row = cc * 16 + srow;
            gl_lds16(A + (size_t)(m0 + row) * D_ + k0 + sg, As + cc * 512);
            gl_lds16(Wm + (size_t)(n0 + row) * D_ + k0 + sg, Bs + cc * 512);
        }
        __syncthreads();  // drains vmcnt (incl. global_load_lds)
        short8 af[4], bf[4];
#pragma unroll
        for (int i = 0; i < 4; ++i) {
            af[i] = *(const short8*)(As + (wr * 64 + i * 16 + ln15) * 32 + quad * 8);
            bf[i] = *(const short8*)(Bs + (wc * 64 + i * 16 + ln15) * 32 + quad * 8);
        }
#pragma unroll
        for (int mt = 0; mt < 4; ++mt)
#pragma unroll
            for (int nt = 0; nt < 4; ++nt)
                acc[mt][nt] = __builtin_amdgcn_mfma_f32_16x16x32_bf16(
                    af[mt], bf[nt], acc[mt][nt], 0, 0, 0);
        __syncthreads();
    }
    // epilogue: C[row=quad*4+r][col=ln15] per frag (m89-verified layout)
#pragma unroll
    for (int mt = 0; mt < 4; ++mt) {
#pragma unroll
        for (int r = 0; r < 4; ++r) {
            const int row = m0 + wr * 64 + mt * 16 + quad * 4 + r;
#pragma unroll
            for (int nt = 0; nt < 4; ++nt) {
                const int col = n0 + wc * 64 + nt * 16 + ln15;
                const float v = acc[mt][nt][r] + bias[col];
                if (OUT_LAYOUT == 0) {
                    const int bb = row >> 11, s = row & (S_ - 1);
                    const int h = col >> 6, dk = col & 63;
                    ((ushort*)outv)[((((size_t)bb * H_ + h) * S_ + s) << 6) + dk] = f2bf(v);
                } else {
                    ((float*)outv)[(size_t)row * D_ + col] = v;
                }
            }
        }
    }
}

// ---------------------------------------------------------------------------
// Flash attention, bf16 MFMA. Block = 256 thr (4 waves), BQ=128 (wave w owns
// q rows w*32..w*32+31 -> softmax state wave-local), k-tiles of 64.
// Qs/Ks async-staged with XOR-swizzled 8-elem groups (kills the stride-128B
// bank collision); Vt = V transposed in LDS (stride 72); Ps = P round-trip
// (C-layout -> A-layout, m120 pattern), stride 72.
// ---------------------------------------------------------------------------
__global__ __launch_bounds__(256) void attn_mfma(const ushort* __restrict__ Qd,
                                                 const ushort* __restrict__ Kd,
                                                 const ushort* __restrict__ Vd,
                                                 const unsigned char* __restrict__ m8,
                                                 ushort* __restrict__ ctx) {
    __shared__ ushort Qs[128 * 64];  // [q][dk] swizzled groups, 16 KB
    __shared__ ushort Ks[64 * 64];   // [k][dk] swizzled groups, 8 KB
    __shared__ ushort Vt[64 * 72];   // [dk][key] padded stride, 9 KB
    __shared__ ushort Ps[128 * 72];  // [q][key] padded stride, 18 KB

    const int t = threadIdx.x, w = t >> 6, lane = t & 63;
    const int ln15 = lane & 15, quad = lane >> 4;
    const int lp = lane & 7, lr8 = lane >> 3;  // staging: phys group, row-in-8
    const int bh = blockIdx.y, b = bh >> 4, h = bh & 15;
    const int q0 = blockIdx.x * 128;

    const ushort* Qb = Qd + (size_t)bh * (S_ * DK_);
    const ushort* Kb = Kd + (size_t)bh * (S_ * DK_);
    const ushort* Vb = Vd + (size_t)bh * (S_ * DK_);
    const unsigned char* mb = m8 + (size_t)b * S_ * S_;

    // stage Q once (async, swizzled: lane fetches logical group lp^lr8)
#pragma unroll
    for (int c = 0; c < 4; ++c) {
        const int cc = w * 4 + c;
        const int row = cc * 8 + lr8;
        const int gl = lp ^ lr8;  // row&7 == lr8
        gl_lds16(Qb + (size_t)(q0 + row) * DK_ + gl * 8, Qs + cc * 512);
    }

    float m_i[2][4], l_i[2][4];
    f32x4 O[2][4] = {};
#pragma unroll
    for (int mt = 0; mt < 2; ++mt)
#pragma unroll
        for (int r = 0; r < 4; ++r) { m_i[mt][r] = -3.0e38f; l_i[mt][r] = 0.0f; }

    for (int kt = 0; kt < S_ / 64; ++kt) {
        const int k0 = kt * 64;
        // stage K (async, swizzled)
#pragma unroll
        for (int c = 0; c < 2; ++c) {
            const int cc = w * 2 + c;
            const int row = cc * 8 + lr8;
            const int gl = lp ^ lr8;
            gl_lds16(Kb + (size_t)(k0 + row) * DK_ + gl * 8, Ks + cc * 512);
        }
        // stage V transposed: thread handles 2 keys x 8 dims
        {
            const int key2 = t & 31, dg = t >> 5;  // dg 0..7
            const ushort8 r0 = *(const ushort8*)(Vb + (size_t)(k0 + 2 * key2) * DK_ + dg * 8);
            const ushort8 r1 = *(const ushort8*)(Vb + (size_t)(k0 + 2 * key2 + 1) * DK_ + dg * 8);
#pragma unroll
            for (int j = 0; j < 8; ++j) {
                const unsigned int p = (unsigned int)r0[j] | ((unsigned int)r1[j] << 16);
                *(unsigned int*)(Vt + (dg * 8 + j) * 72 + 2 * key2) = p;
            }
        }
        __syncthreads();

        // ---- S = Q K^T  (M=32/wave, N=64, K=64 -> 2 ks steps, 16 MFMAs)
        f32x4 sc[2][4] = {};
#pragma unroll
        for (int ks = 0; ks < 2; ++ks) {
            short8 aq[2], bk[4];
#pragma unroll
            for (int mt = 0; mt < 2; ++mt) {
                const int row = w * 32 + mt * 16 + ln15;
                const int g = (ks * 4 + quad) ^ (row & 7);
                aq[mt] = *(const short8*)(Qs + row * 64 + g * 8);
            }
#pragma unroll
            for (int nt = 0; nt < 4; ++nt) {
                const int row = nt * 16 + ln15;
                const int g = (ks * 4 + quad) ^ (row & 7);
                bk[nt] = *(const short8*)(Ks + row * 64 + g * 8);
            }
#pragma unroll
            for (int mt = 0; mt < 2; ++mt)
#pragma unroll
                for (int nt = 0; nt < 4; ++nt)
                    sc[mt][nt] = __builtin_amdgcn_mfma_f32_16x16x32_bf16(
                        aq[mt], bk[nt], sc[mt][nt], 0, 0, 0);
        }

        // ---- scale + mask + online softmax (row = quad's 16 lanes)
#pragma unroll
        for (int mt = 0; mt < 2; ++mt) {
#pragma unroll
            for (int r = 0; r < 4; ++r) {
                const int qg = q0 + w * 32 + mt * 16 + quad * 4 + r;
                const unsigned char* mrow = mb + (size_t)qg * S_ + k0 + ln15;
                float v[4];
#pragma unroll
                for (int nt = 0; nt < 4; ++nt)
                    v[nt] = mrow[nt * 16] ? sc[mt][nt][r] * 0.125f : -1.0e9f;
                float mx = fmaxf(fmaxf(v[0], v[1]), fmaxf(v[2], v[3]));
#pragma unroll
                for (int s = 8; s >= 1; s >>= 1) mx = fmaxf(mx, __shfl_xor(mx, s, 64));
                const float mnew = fmaxf(m_i[mt][r], mx);
                const float alpha = __expf(m_i[mt][r] - mnew);
                m_i[mt][r] = mnew;
                float rs = 0.0f;
#pragma unroll
                for (int nt = 0; nt < 4; ++nt) {
                    v[nt] = __expf(v[nt] - mnew);
                    rs += v[nt];
                }
#pragma unroll
                for (int s = 8; s >= 1; s >>= 1) rs += __shfl_xor(rs, s, 64);
                l_i[mt][r] = l_i[mt][r] * alpha + rs;
#pragma unroll
                for (int nt = 0; nt < 4; ++nt) O[mt][nt][r] *= alpha;
                // P -> LDS in A-operand layout (bf16)
                const int prow = w * 32 + mt * 16 + quad * 4 + r;
#pragma unroll
                for (int nt = 0; nt < 4; ++nt)
                    Ps[prow * 72 + nt * 16 + ln15] = f2bf(v[nt]);
            }
        }
        // Ps is wave-private; in-wave lgkmcnt ordering suffices (no barrier)

        // ---- O += P V   (M=32, N=64 dims, K=64 keys -> 2 ks, 16 MFMAs)
#pragma unroll
        for (int ks = 0; ks < 2; ++ks) {
            short8 ap[2], bv[4];
#pragma unroll
            for (int mt = 0; mt < 2; ++mt) {
                const int row = w * 32 + mt * 16 + ln15;
                ap[mt] = *(const short8*)(Ps + row * 72 + ks * 32 + quad * 8);
            }
#pragma unroll
            for (int nt = 0; nt < 4; ++nt) {
                const int drow = nt * 16 + ln15;
                bv[nt] = *(const short8*)(Vt + drow * 72 + ks * 32 + quad * 8);
            }
#pragma unroll
            for (int mt = 0; mt < 2; ++mt)
#pragma unroll
                for (int nt = 0; nt < 4; ++nt)
                    O[mt][nt] = __builtin_amdgcn_mfma_f32_16x16x32_bf16(
                        ap[mt], bv[nt], O[mt][nt], 0, 0, 0);
        }
        __syncthreads();  // protect Ks/Vt for next tile
    }

    // finalize: ctx[b][s][h*64+dim] = O/l  (bf16, feeds out-proj GEMM)
#pragma unroll
    for (int mt = 0; mt < 2; ++mt) {
#pragma unroll
        for (int r = 0; r < 4; ++r) {
            const int qg = q0 + w * 32 + mt * 16 + quad * 4 + r;
            const float inv = 1.0f / l_i[mt][r];
#pragma unroll
            for (int nt = 0; nt < 4; ++nt) {
                const int dim = nt * 16 + ln15;
                ctx[((size_t)b * S_ + qg) * D_ + h * DK_ + dim] = f2bf(O[mt][nt][r] * inv);
            }
        }
    }
}

// ---------------------------------------------------------------------------
extern "C" void kernel_launch(void* const* d_in, const int* in_sizes, int n_in,
                              void* d_out, int out_size, void* d_ws, size_t ws_size,
                              hipStream_t stream) {
    (void)in_sizes; (void)n_in; (void)out_size; (void)ws_size;
    const float* query = (const float*)d_in[0];
    const float* key_  = (const float*)d_in[1];
    const float* value = (const float*)d_in[2];
    const int*   mask  = (const int*)d_in[3];
    const float* Wq = (const float*)d_in[4];
    const float* bq = (const float*)d_in[5];
    const float* Wk = (const float*)d_in[6];
    const float* bk = (const float*)d_in[7];
    const float* Wv = (const float*)d_in[8];
    const float* bv = (const float*)d_in[9];
    const float* Wo = (const float*)d_in[10];
    const float* bo = (const float*)d_in[11];
    float* out = (float*)d_out;

    const size_t nX = (size_t)B_ * S_ * D_;  // 8,388,608
    const size_t nW = (size_t)D_ * D_;       // 1,048,576
    ushort* qb  = (ushort*)d_ws;       // 16 MiB; reused as ctx after Q-proj
    ushort* kb  = qb + nX;
    ushort* vb  = kb + nX;
    ushort* Wqb = vb + nX;
    ushort* Wkb = Wqb + nW;
    ushort* Wvb = Wkb + nW;
    ushort* Wob = Wvb + nW;
    ushort* Qd  = Wob + nW;
    ushort* Kd  = Qd + nX;
    ushort* Vd  = Kd + nX;
    unsigned char* m8 = (unsigned char*)(Vd + nX);  // 16 MiB; total ws = 120 MiB
    ushort* ctx = qb;

    cast_bf16_x8<<<4096, 256, 0, stream>>>(query, qb, (int)nX);
    cast_bf16_x8<<<4096, 256, 0, stream>>>(key_,  kb, (int)nX);
    cast_bf16_x8<<<4096, 256, 0, stream>>>(value, vb, (int)nX);
    cast_bf16_x8<<<512, 256, 0, stream>>>(Wq, Wqb, (int)nW);
    cast_bf16_x8<<<512, 256, 0, stream>>>(Wk, Wkb, (int)nW);
    cast_bf16_x8<<<512, 256, 0, stream>>>(Wv, Wvb, (int)nW);
    cast_bf16_x8<<<512, 256, 0, stream>>>(Wo, Wob, (int)nW);
    mask_to_u8<<<16384, 256, 0, stream>>>(mask, (unsigned int*)m8, B_ * S_ * S_ / 4);

    dim3 gp(D_ / 128, (B_ * S_) / 128);  // (8, 64)
    gemm_bt_mfma<0><<<gp, 256, 0, stream>>>(qb, Wqb, bq, Qd);
    gemm_bt_mfma<0><<<gp, 256, 0, stream>>>(kb, Wkb, bk, Kd);
    gemm_bt_mfma<0><<<gp, 256, 0, stream>>>(vb, Wvb, bv, Vd);

    dim3 ga(S_ / 128, B_ * H_);  // (16, 64)
    attn_mfma<<<ga, 256, 0, stream>>>(Qd, Kd, Vd, m8, ctx);

    gemm_bt_mfma<1><<<gp, 256, 0, stream>>>(ctx, Wob, bo, out);
}